// Round 5
// baseline (154.271 us; speedup 1.0000x reference)
//
#include <hip/hip_runtime.h>
#include <math.h>

// ---------------- constants ----------------
#define WS 11
#define PAD 10
#define NC 48            // 16 batch * 3 channels
#define C1V 1.0e-4f
#define C2V 9.0e-4f
#define BROWS 48         // circular LDS row-plane depth (42 live + write window <= 48)
#define RST 33           // float4 row stride

struct Params { float g[WS]; };
struct ROff { int off[5]; int cnt[5]; float inv[5]; };

// wrap y (0..143) into [0,48)
__device__ __forceinline__ int wrap48(int y) {
    if (y >= 96) y -= 96;
    if (y >= 48) y -= 48;
    return y;
}

// ---- one row-conv unit: 4 output cols, channels (s, d, s^2, d^2) ----
__device__ __forceinline__ void row_conv_unit(
    const float* __restrict__ rowa, const float* __restrict__ rowb,
    const int xq[4], int cg, float4* __restrict__ rprow, const Params& P)
{
    float sv[16], dv[16];
#pragma unroll
    for (int q = 0; q < 4; ++q) {
        const float4 va = *(const float4*)(rowa + xq[q]);
        const float4 vb = *(const float4*)(rowb + xq[q]);
        sv[q*4+0]=va.x+vb.x; dv[q*4+0]=va.x-vb.x;
        sv[q*4+1]=va.y+vb.y; dv[q*4+1]=va.y-vb.y;
        sv[q*4+2]=va.z+vb.z; dv[q*4+2]=va.z-vb.z;
        sv[q*4+3]=va.w+vb.w; dv[q*4+3]=va.w-vb.w;
    }
    float m0[4]={0,0,0,0}, m1[4]={0,0,0,0}, m2[4]={0,0,0,0}, m3[4]={0,0,0,0};
#pragma unroll
    for (int i = 0; i < 14; ++i) {
        const float s = sv[i], d = dv[i];
        const float ss = s*s, dd = d*d;
#pragma unroll
        for (int j = 0; j < 4; ++j) {
            const int k = i - j;
            if (k >= 0 && k < WS) {
                const float g = P.g[k];
                m0[j]+=g*s; m1[j]+=g*d; m2[j]+=g*ss; m3[j]+=g*dd;
            }
        }
    }
#pragma unroll
    for (int j = 0; j < 4; ++j)
        rprow[cg*4 + j] = make_float4(m0[j], m1[j], m2[j], m3[j]);
}

// ---------------- sliding-strip SSIM (+pool) kernel ----------------
// Each block: 32-wide strip, CH chunks of 32 output rows; 48-row circular
// LDS plane of row-conv results. grid: (tilesX*tilesY, NC); block: 256.
template<int CH, int POOL>
__global__ __launch_bounds__(256, 6) void ssim_strip_kernel(
    const float* __restrict__ img1, const float* __restrict__ img2,
    float* __restrict__ pool1, float* __restrict__ pool2,
    int H, int OH, int tilesX, Params P,
    float2* __restrict__ partial, int partial_off)
{
    __shared__ float4 rp[BROWS][RST];
    __shared__ float reds[4], redc[4];
    const int tid   = threadIdx.x;
    const int tileX = blockIdx.x % tilesX;
    const int ty    = blockIdx.x / tilesX;
    const int img   = blockIdx.y;
    const size_t ib = (size_t)img * H * H;
    const float* __restrict__ p1 = img1 + ib;
    const float* __restrict__ p2 = img2 + ib;
    const int ox0 = tileX * 32;
    const int oy0 = ty * (CH * 32);

    // fixed per-thread roles
    const int r_unit = tid >> 3;          // 0..31: row-conv row within chunk
    const int cg     = tid & 7;           // row-conv col group
    int xq[4];                            // clamped, constant across all rows
#pragma unroll
    for (int q = 0; q < 4; ++q) xq[q] = min(ox0 + cg*4 + q*4, H - 4);

    const int cc  = tid & 31;             // col-conv column
    const int r0c = (tid >> 5) * 4;       // col-conv first row in chunk

    // preload strip-relative rows 0..9 (slots 0..9)
    if (tid < 80) {
        const int y = min(oy0 + r_unit, H - 1);
        row_conv_unit(p1 + (size_t)y*H, p2 + (size_t)y*H, xq, cg,
                      &rp[r_unit][0], P);
    }

    float ssim_acc = 0.f, cs_acc = 0.f;

    for (int t = 0; t < CH; ++t) {
        // ---- row conv: rows t*32+10 .. t*32+41 (exactly 1 unit/thread) ----
        {
            const int Y = t*32 + 10 + r_unit;
            const int y = min(oy0 + Y, H - 1);
            row_conv_unit(p1 + (size_t)y*H, p2 + (size_t)y*H, xq, cg,
                          &rp[wrap48(Y)][0], P);
        }
        __syncthreads();

        // ---- col conv + SSIM: 4 consecutive rows per thread ----
        const int base = wrap48(t*32 + r0c);
        float A0[4]={0,0,0,0}, A1[4]={0,0,0,0}, A2[4]={0,0,0,0}, A3[4]={0,0,0,0};
#pragma unroll
        for (int k = 0; k < 14; ++k) {
            int idx = base + k;
            if (idx >= BROWS) idx -= BROWS;
            const float4 v = rp[idx][cc];
#pragma unroll
            for (int j = 0; j < 4; ++j) {
                const int tt = k - j;
                if (tt >= 0 && tt < WS) {
                    const float g = P.g[tt];
                    A0[j]+=g*v.x; A1[j]+=g*v.y; A2[j]+=g*v.z; A3[j]+=g*v.w;
                }
            }
        }
        const int ox = ox0 + cc;
#pragma unroll
        for (int j = 0; j < 4; ++j) {
            const int oy = oy0 + t*32 + r0c + j;
            if (oy < OH && ox < OH) {     // OW == OH (square)
                const float ms = A0[j], md = A1[j], Es = A2[j], Ed = A3[j];
                const float ms2 = ms*ms, md2 = md*md;
                const float mu12 = 0.25f * (ms2 - md2);
                const float musq = 0.5f  * (ms2 + md2);             // mu1^2+mu2^2
                const float v1 = 0.5f * (Es - Ed) - 2.f*mu12 + C2V; // 2*sig12+C2
                const float v2 = 0.5f * (Es + Ed) - musq + C2V;     // sig1+sig2+C2
                const float rv2 = __builtin_amdgcn_rcpf(v2);
                const float cs  = v1 * rv2;
                const float ssim = (2.f*mu12 + C1V) *
                                   __builtin_amdgcn_rcpf(musq + C1V) * cs;
                ssim_acc += ssim;
                cs_acc   += cs;
            }
        }

        // ---- fused 2x2 avg pool of this chunk's 32x32 core (1 out/thread) ----
        if (POOL) {
            const int px = tid & 15, py = tid >> 4;
            const int yy = oy0 + t*32 + 2*py;
            const int xx = ox0 + 2*px;
            const float2 a0 = *(const float2*)(p1 + (size_t)yy*H + xx);
            const float2 a1 = *(const float2*)(p1 + (size_t)(yy+1)*H + xx);
            const float2 b0 = *(const float2*)(p2 + (size_t)yy*H + xx);
            const float2 b1 = *(const float2*)(p2 + (size_t)(yy+1)*H + xx);
            const int h = H >> 1;
            const size_t ob = (size_t)img*h*h +
                              (size_t)(((oy0 + t*32) >> 1) + py)*h + (ox0 >> 1) + px;
            pool1[ob] = 0.25f * (a0.x + a0.y + a1.x + a1.y);
            pool2[ob] = 0.25f * (b0.x + b0.y + b1.x + b1.y);
        }
        __syncthreads();   // protect read window before next chunk's writes
    }

    // ---- deterministic block reduction -> one partial per block ----
#pragma unroll
    for (int off = 32; off > 0; off >>= 1) {
        ssim_acc += __shfl_down(ssim_acc, off);
        cs_acc   += __shfl_down(cs_acc, off);
    }
    const int wave = tid >> 6, lane = tid & 63;
    if (lane == 0) { reds[wave] = ssim_acc; redc[wave] = cs_acc; }
    __syncthreads();
    if (tid == 0) {
        const float s   = reds[0] + reds[1] + reds[2] + reds[3];
        const float cc2 = redc[0] + redc[1] + redc[2] + redc[3];
        partial[(size_t)partial_off + (size_t)blockIdx.y * gridDim.x + blockIdx.x] =
            make_float2(s, cc2);
    }
}

// ---------------- single fused reduce over all levels + final product ----------------
__global__ __launch_bounds__(256) void reduce_final_kernel(
    const float2* __restrict__ partial, ROff ro, float* __restrict__ out)
{
    __shared__ float sS[5], sC[5];
    __shared__ float reds[4], redc[4];
    const int tid = threadIdx.x;
    for (int l = 0; l < 5; ++l) {
        float s = 0.f, c = 0.f;
        for (int i = tid; i < ro.cnt[l]; i += 256) {
            const float2 v = partial[ro.off[l] + i];
            s += v.x; c += v.y;
        }
#pragma unroll
        for (int off = 32; off > 0; off >>= 1) {
            s += __shfl_down(s, off);
            c += __shfl_down(c, off);
        }
        const int wave = tid >> 6, lane = tid & 63;
        if (lane == 0) { reds[wave] = s; redc[wave] = c; }
        __syncthreads();
        if (tid == 0) {
            sS[l] = (reds[0] + reds[1] + reds[2] + reds[3]) * ro.inv[l];
            sC[l] = (redc[0] + redc[1] + redc[2] + redc[3]) * ro.inv[l];
        }
        __syncthreads();
    }
    if (tid == 0) {
        const float w[5] = {0.0448f, 0.2856f, 0.3001f, 0.2363f, 0.1333f};
        float prod = 1.f;
#pragma unroll
        for (int i = 0; i < 4; ++i)
            prod *= powf((sC[i] + 1.f) * 0.5f, w[i]);
        prod *= powf((sS[4] + 1.f) * 0.5f, w[4]);
        out[0] = prod;
    }
}

// ---------------- host launch ----------------
extern "C" void kernel_launch(void* const* d_in, const int* in_sizes, int n_in,
                              void* d_out, int out_size, void* d_ws, size_t ws_size,
                              hipStream_t stream)
{
    const float* img1 = (const float*)d_in[0];
    const float* img2 = (const float*)d_in[1];
    float* out = (float*)d_out;
    float* ws  = (float*)d_ws;

    // Gaussian window (sigma = 1.5), normalized
    Params P;
    {
        double g[WS], sum = 0.0;
        for (int i = 0; i < WS; ++i) {
            double x = (double)i - (WS / 2);
            g[i] = exp(-x * x / (2.0 * 1.5 * 1.5));
            sum += g[i];
        }
        for (int i = 0; i < WS; ++i) P.g[i] = (float)(g[i] / sum);
    }

    // workspace layout: pyramid levels 1..4 (both images), then partials
    float* p1[5]; float* p2[5];
    p1[0] = (float*)img1; p2[0] = (float*)img2;
    size_t o = 0;
    for (int l = 1; l < 5; ++l) {
        const int H = 512 >> l;
        p1[l] = ws + o; o += (size_t)NC * H * H;
        p2[l] = ws + o; o += (size_t)NC * H * H;
    }
    float2* partial = (float2*)(ws + o);
    (void)ws_size; (void)in_sizes; (void)n_in; (void)out_size;

    const int CHv[5] = {4, 2, 1, 1, 1};   // chunks per strip, per level
    ROff ro;
    {
        int off = 0;
        for (int l = 0; l < 5; ++l) {
            const int H = 512 >> l, OH = H - PAD;
            const int tilesX = (OH + 31) / 32;
            const int tilesY = (OH + CHv[l]*32 - 1) / (CHv[l]*32);
            ro.off[l] = off;
            ro.cnt[l] = tilesX * tilesY * NC;
            ro.inv[l] = 1.f / ((float)NC * OH * OH);
            off += ro.cnt[l];
        }
    }

    for (int l = 0; l < 5; ++l) {
        const int H = 512 >> l, OH = H - PAD;
        const int tilesX = (OH + 31) / 32;
        const int tilesY = (OH + CHv[l]*32 - 1) / (CHv[l]*32);
        const dim3 grid(tilesX * tilesY, NC);
        switch (l) {
        case 0:
            ssim_strip_kernel<4,1><<<grid, 256, 0, stream>>>(
                p1[0], p2[0], p1[1], p2[1], H, OH, tilesX, P, partial, ro.off[0]);
            break;
        case 1:
            ssim_strip_kernel<2,1><<<grid, 256, 0, stream>>>(
                p1[1], p2[1], p1[2], p2[2], H, OH, tilesX, P, partial, ro.off[1]);
            break;
        case 2:
            ssim_strip_kernel<1,1><<<grid, 256, 0, stream>>>(
                p1[2], p2[2], p1[3], p2[3], H, OH, tilesX, P, partial, ro.off[2]);
            break;
        case 3:
            ssim_strip_kernel<1,1><<<grid, 256, 0, stream>>>(
                p1[3], p2[3], p1[4], p2[4], H, OH, tilesX, P, partial, ro.off[3]);
            break;
        default:
            ssim_strip_kernel<1,0><<<grid, 256, 0, stream>>>(
                p1[4], p2[4], nullptr, nullptr, H, OH, tilesX, P, partial, ro.off[4]);
            break;
        }
    }

    reduce_final_kernel<<<1, 256, 0, stream>>>(partial, ro, out);
}

// Round 6
// 148.414 us; speedup vs baseline: 1.0395x; 1.0395x over previous
//
#include <hip/hip_runtime.h>
#include <math.h>

// ---------------- constants ----------------
#define WS 11
#define PAD 10
#define NC 48            // 16 batch * 3 channels
#define C1V 1.0e-4f
#define C2V 9.0e-4f
#define PLROWS 42        // fixed row-conv plane: 32 outputs + 10 carry
#define RST 33           // float4 row stride

struct Params { float g[WS]; };
struct ROff { int off[5]; int cnt[5]; float inv[5]; };

// ---- one row-conv unit: 4 output cols, channels (s, d, s^2, d^2) ----
__device__ __forceinline__ void row_conv_unit(
    const float* __restrict__ rowa, const float* __restrict__ rowb,
    const int xq[4], int cg, float4* __restrict__ rprow, const Params& P)
{
    float sv[16], dv[16];
#pragma unroll
    for (int q = 0; q < 4; ++q) {
        const float4 va = *(const float4*)(rowa + xq[q]);
        const float4 vb = *(const float4*)(rowb + xq[q]);
        sv[q*4+0]=va.x+vb.x; dv[q*4+0]=va.x-vb.x;
        sv[q*4+1]=va.y+vb.y; dv[q*4+1]=va.y-vb.y;
        sv[q*4+2]=va.z+vb.z; dv[q*4+2]=va.z-vb.z;
        sv[q*4+3]=va.w+vb.w; dv[q*4+3]=va.w-vb.w;
    }
    float m0[4]={0,0,0,0}, m1[4]={0,0,0,0}, m2[4]={0,0,0,0}, m3[4]={0,0,0,0};
#pragma unroll
    for (int i = 0; i < 14; ++i) {
        const float s = sv[i], d = dv[i];
        const float ss = s*s, dd = d*d;
#pragma unroll
        for (int j = 0; j < 4; ++j) {
            const int k = i - j;
            if (k >= 0 && k < WS) {
                const float g = P.g[k];
                m0[j]+=g*s; m1[j]+=g*d; m2[j]+=g*ss; m3[j]+=g*dd;
            }
        }
    }
#pragma unroll
    for (int j = 0; j < 4; ++j)
        rprow[cg*4 + j] = make_float4(m0[j], m1[j], m2[j], m3[j]);
}

// ---------------- sliding-strip SSIM (+pool) kernel ----------------
// Each block: 32-wide strip, CH chunks of 32 output rows. Fixed 42-row LDS
// plane; after each chunk, rows 32..41 are copied to slots 0..9 (carry).
// All LDS row indices are thread-constant or unrolled-constant -> immediate
// offsets (the R5 mod-48 scheme broke this and spilled; never again).
// grid: (tilesX*tilesY, NC); block: 256.
template<int CH, int POOL>
__global__ __launch_bounds__(256, 6) void ssim_strip_kernel(
    const float* __restrict__ img1, const float* __restrict__ img2,
    float* __restrict__ pool1, float* __restrict__ pool2,
    int H, int OH, int tilesX, Params P,
    float2* __restrict__ partial, int partial_off)
{
    __shared__ float4 rp[PLROWS][RST];
    __shared__ float reds[4], redc[4];
    const int tid   = threadIdx.x;
    const int tileX = blockIdx.x % tilesX;
    const int ty    = blockIdx.x / tilesX;
    const int img   = blockIdx.y;
    const size_t ib = (size_t)img * H * H;
    const float* __restrict__ p1 = img1 + ib;
    const float* __restrict__ p2 = img2 + ib;
    const int ox0 = tileX * 32;
    const int oy0 = ty * (CH * 32);

    // fixed per-thread roles
    const int r_unit = tid >> 3;          // 0..31: row-conv row within chunk
    const int cg     = tid & 7;           // row-conv col group
    int xq[4];                            // clamped, constant across all rows
#pragma unroll
    for (int q = 0; q < 4; ++q) xq[q] = min(ox0 + cg*4 + q*4, H - 4);

    const int cc  = tid & 31;             // col-conv column
    const int r0c = (tid >> 5) * 4;       // col-conv first row in chunk

    // preload strip rows 0..9 -> slots 0..9
    if (tid < 80) {
        const int y = min(oy0 + r_unit, H - 1);
        row_conv_unit(p1 + (size_t)y*H, p2 + (size_t)y*H, xq, cg,
                      &rp[r_unit][0], P);
    }

    float ssim_acc = 0.f, cs_acc = 0.f;

    for (int t = 0; t < CH; ++t) {
        // ---- row conv: rows t*32+10 .. t*32+41 -> slots 10..41 (1/thread) ----
        {
            const int y = min(oy0 + t*32 + 10 + r_unit, H - 1);
            row_conv_unit(p1 + (size_t)y*H, p2 + (size_t)y*H, xq, cg,
                          &rp[10 + r_unit][0], P);
        }
        __syncthreads();

        // ---- col conv + SSIM: 4 consecutive rows per thread ----
        float A0[4]={0,0,0,0}, A1[4]={0,0,0,0}, A2[4]={0,0,0,0}, A3[4]={0,0,0,0};
#pragma unroll
        for (int k = 0; k < 14; ++k) {
            const float4 v = rp[r0c + k][cc];   // base + k*528B immediate
#pragma unroll
            for (int j = 0; j < 4; ++j) {
                const int tt = k - j;
                if (tt >= 0 && tt < WS) {
                    const float g = P.g[tt];
                    A0[j]+=g*v.x; A1[j]+=g*v.y; A2[j]+=g*v.z; A3[j]+=g*v.w;
                }
            }
        }
        const int ox = ox0 + cc;
#pragma unroll
        for (int j = 0; j < 4; ++j) {
            const int oy = oy0 + t*32 + r0c + j;
            if (oy < OH && ox < OH) {     // OW == OH (square)
                const float ms = A0[j], md = A1[j], Es = A2[j], Ed = A3[j];
                const float ms2 = ms*ms, md2 = md*md;
                const float mu12 = 0.25f * (ms2 - md2);
                const float musq = 0.5f  * (ms2 + md2);             // mu1^2+mu2^2
                const float v1 = 0.5f * (Es - Ed) - 2.f*mu12 + C2V; // 2*sig12+C2
                const float v2 = 0.5f * (Es + Ed) - musq + C2V;     // sig1+sig2+C2
                const float rv2 = __builtin_amdgcn_rcpf(v2);
                const float cs  = v1 * rv2;
                const float ssim = (2.f*mu12 + C1V) *
                                   __builtin_amdgcn_rcpf(musq + C1V) * cs;
                ssim_acc += ssim;
                cs_acc   += cs;
            }
        }

        // ---- fused 2x2 avg pool of this chunk's 32x32 core (1 out/thread) ----
        if (POOL) {
            const int px = tid & 15, py = tid >> 4;
            const int yy = oy0 + t*32 + 2*py;
            const int xx = ox0 + 2*px;
            const float2 a0 = *(const float2*)(p1 + (size_t)yy*H + xx);
            const float2 a1 = *(const float2*)(p1 + (size_t)(yy+1)*H + xx);
            const float2 b0 = *(const float2*)(p2 + (size_t)yy*H + xx);
            const float2 b1 = *(const float2*)(p2 + (size_t)(yy+1)*H + xx);
            const int h = H >> 1;
            const size_t ob = (size_t)img*h*h +
                              (size_t)(((oy0 + t*32) >> 1) + py)*h + (ox0 >> 1) + px;
            pool1[ob] = 0.25f * (a0.x + a0.y + a1.x + a1.y);
            pool2[ob] = 0.25f * (b0.x + b0.y + b1.x + b1.y);
        }

        // ---- carry: rows t*32+32..41 (slots 32..41) -> slots 0..9 ----
        if (t + 1 < CH) {
            __syncthreads();              // col-conv reads of slots 0..9 done
            if (tid < 320) {
                const int r = tid >> 5, c = tid & 31;
                rp[r][c] = rp[32 + r][c]; // disjoint rows: no intra-phase race
            }
            __syncthreads();              // carry done before next row-conv
        }
    }

    // ---- deterministic block reduction -> one partial per block ----
#pragma unroll
    for (int off = 32; off > 0; off >>= 1) {
        ssim_acc += __shfl_down(ssim_acc, off);
        cs_acc   += __shfl_down(cs_acc, off);
    }
    const int wave = tid >> 6, lane = tid & 63;
    if (lane == 0) { reds[wave] = ssim_acc; redc[wave] = cs_acc; }
    __syncthreads();
    if (tid == 0) {
        const float s   = reds[0] + reds[1] + reds[2] + reds[3];
        const float cc2 = redc[0] + redc[1] + redc[2] + redc[3];
        partial[(size_t)partial_off + (size_t)blockIdx.y * gridDim.x + blockIdx.x] =
            make_float2(s, cc2);
    }
}

// ---------------- single fused reduce over all levels + final product ----------------
__global__ __launch_bounds__(256) void reduce_final_kernel(
    const float2* __restrict__ partial, ROff ro, float* __restrict__ out)
{
    __shared__ float sS[5], sC[5];
    __shared__ float reds[4], redc[4];
    const int tid = threadIdx.x;
    for (int l = 0; l < 5; ++l) {
        float s = 0.f, c = 0.f;
        for (int i = tid; i < ro.cnt[l]; i += 256) {
            const float2 v = partial[ro.off[l] + i];
            s += v.x; c += v.y;
        }
#pragma unroll
        for (int off = 32; off > 0; off >>= 1) {
            s += __shfl_down(s, off);
            c += __shfl_down(c, off);
        }
        const int wave = tid >> 6, lane = tid & 63;
        if (lane == 0) { reds[wave] = s; redc[wave] = c; }
        __syncthreads();
        if (tid == 0) {
            sS[l] = (reds[0] + reds[1] + reds[2] + reds[3]) * ro.inv[l];
            sC[l] = (redc[0] + redc[1] + redc[2] + redc[3]) * ro.inv[l];
        }
        __syncthreads();
    }
    if (tid == 0) {
        const float w[5] = {0.0448f, 0.2856f, 0.3001f, 0.2363f, 0.1333f};
        float prod = 1.f;
#pragma unroll
        for (int i = 0; i < 4; ++i)
            prod *= powf((sC[i] + 1.f) * 0.5f, w[i]);
        prod *= powf((sS[4] + 1.f) * 0.5f, w[4]);
        out[0] = prod;
    }
}

// ---------------- host launch ----------------
extern "C" void kernel_launch(void* const* d_in, const int* in_sizes, int n_in,
                              void* d_out, int out_size, void* d_ws, size_t ws_size,
                              hipStream_t stream)
{
    const float* img1 = (const float*)d_in[0];
    const float* img2 = (const float*)d_in[1];
    float* out = (float*)d_out;
    float* ws  = (float*)d_ws;

    // Gaussian window (sigma = 1.5), normalized
    Params P;
    {
        double g[WS], sum = 0.0;
        for (int i = 0; i < WS; ++i) {
            double x = (double)i - (WS / 2);
            g[i] = exp(-x * x / (2.0 * 1.5 * 1.5));
            sum += g[i];
        }
        for (int i = 0; i < WS; ++i) P.g[i] = (float)(g[i] / sum);
    }

    // workspace layout: pyramid levels 1..4 (both images), then partials
    float* p1[5]; float* p2[5];
    p1[0] = (float*)img1; p2[0] = (float*)img2;
    size_t o = 0;
    for (int l = 1; l < 5; ++l) {
        const int H = 512 >> l;
        p1[l] = ws + o; o += (size_t)NC * H * H;
        p2[l] = ws + o; o += (size_t)NC * H * H;
    }
    float2* partial = (float2*)(ws + o);
    (void)ws_size; (void)in_sizes; (void)n_in; (void)out_size;

    const int CHv[5] = {4, 2, 1, 1, 1};   // chunks per strip, per level
    ROff ro;
    {
        int off = 0;
        for (int l = 0; l < 5; ++l) {
            const int H = 512 >> l, OH = H - PAD;
            const int tilesX = (OH + 31) / 32;
            const int tilesY = (OH + CHv[l]*32 - 1) / (CHv[l]*32);
            ro.off[l] = off;
            ro.cnt[l] = tilesX * tilesY * NC;
            ro.inv[l] = 1.f / ((float)NC * OH * OH);
            off += ro.cnt[l];
        }
    }

    for (int l = 0; l < 5; ++l) {
        const int H = 512 >> l, OH = H - PAD;
        const int tilesX = (OH + 31) / 32;
        const int tilesY = (OH + CHv[l]*32 - 1) / (CHv[l]*32);
        const dim3 grid(tilesX * tilesY, NC);
        switch (l) {
        case 0:
            ssim_strip_kernel<4,1><<<grid, 256, 0, stream>>>(
                p1[0], p2[0], p1[1], p2[1], H, OH, tilesX, P, partial, ro.off[0]);
            break;
        case 1:
            ssim_strip_kernel<2,1><<<grid, 256, 0, stream>>>(
                p1[1], p2[1], p1[2], p2[2], H, OH, tilesX, P, partial, ro.off[1]);
            break;
        case 2:
            ssim_strip_kernel<1,1><<<grid, 256, 0, stream>>>(
                p1[2], p2[2], p1[3], p2[3], H, OH, tilesX, P, partial, ro.off[2]);
            break;
        case 3:
            ssim_strip_kernel<1,1><<<grid, 256, 0, stream>>>(
                p1[3], p2[3], p1[4], p2[4], H, OH, tilesX, P, partial, ro.off[3]);
            break;
        default:
            ssim_strip_kernel<1,0><<<grid, 256, 0, stream>>>(
                p1[4], p2[4], nullptr, nullptr, H, OH, tilesX, P, partial, ro.off[4]);
            break;
        }
    }

    reduce_final_kernel<<<1, 256, 0, stream>>>(partial, ro, out);
}

// Round 7
// 105.220 us; speedup vs baseline: 1.4662x; 1.4105x over previous
//
#include <hip/hip_runtime.h>
#include <math.h>

// ---------------- constants ----------------
#define WS 11
#define PAD 10
#define NC 48            // 16 batch * 3 channels
#define C1V 1.0e-4f
#define C2V 9.0e-4f
#define PLROWS 42        // fixed row-conv plane: 32 outputs + 10 carry
#define RST 33           // float4 row stride

struct Params { float g[WS]; };
struct ROff { int off[5]; int cnt[5]; float inv[5]; };

// ---- one row-conv unit: 4 output cols, channels (s, d, s^2, d^2) ----
// Consumes each float4 pair immediately after load (8 window floats live at a
// time instead of 32) to keep register pressure ~50 VGPR. NO launch-bounds cap
// below that: R5/R6 showed a cap -> ~120MB of scratch spill traffic.
__device__ __forceinline__ void row_conv_unit(
    const float* __restrict__ rowa, const float* __restrict__ rowb,
    const int xq[4], int cg, float4* __restrict__ rprow, const Params& P)
{
    float m0[4]={0,0,0,0}, m1[4]={0,0,0,0}, m2[4]={0,0,0,0}, m3[4]={0,0,0,0};
#pragma unroll
    for (int q = 0; q < 4; ++q) {
        const float4 va = *(const float4*)(rowa + xq[q]);
        const float4 vb = *(const float4*)(rowb + xq[q]);
        const float fa[4] = {va.x, va.y, va.z, va.w};
        const float fb[4] = {vb.x, vb.y, vb.z, vb.w};
#pragma unroll
        for (int e = 0; e < 4; ++e) {
            const int i = q * 4 + e;                 // window position 0..15
            const float s = fa[e] + fb[e], d = fa[e] - fb[e];
            const float ss = s * s, dd = d * d;
#pragma unroll
            for (int j = 0; j < 4; ++j) {
                const int k = i - j;
                if (k >= 0 && k < WS) {
                    const float g = P.g[k];
                    m0[j] += g * s;  m1[j] += g * d;
                    m2[j] += g * ss; m3[j] += g * dd;
                }
            }
        }
    }
#pragma unroll
    for (int j = 0; j < 4; ++j)
        rprow[cg*4 + j] = make_float4(m0[j], m1[j], m2[j], m3[j]);
}

// ---------------- sliding-strip SSIM (+pool) kernel ----------------
// Each block: 32-wide strip, CH chunks of 32 output rows. Fixed 42-row LDS
// plane; after each chunk, rows 32..41 are copied to slots 0..9 (carry).
// All LDS row indices are thread-constant or unrolled-constant -> immediate
// offsets. grid: (tilesX*tilesY, NC); block: 256.
template<int CH, int POOL>
__global__ __launch_bounds__(256, 4) void ssim_strip_kernel(
    const float* __restrict__ img1, const float* __restrict__ img2,
    float* __restrict__ pool1, float* __restrict__ pool2,
    int H, int OH, int tilesX, Params P,
    float2* __restrict__ partial, int partial_off)
{
    __shared__ float4 rp[PLROWS][RST];
    __shared__ float reds[4], redc[4];
    const int tid   = threadIdx.x;
    const int tileX = blockIdx.x % tilesX;
    const int ty    = blockIdx.x / tilesX;
    const int img   = blockIdx.y;
    const size_t ib = (size_t)img * H * H;
    const float* __restrict__ p1 = img1 + ib;
    const float* __restrict__ p2 = img2 + ib;
    const int ox0 = tileX * 32;
    const int oy0 = ty * (CH * 32);

    // fixed per-thread roles
    const int r_unit = tid >> 3;          // 0..31: row-conv row within chunk
    const int cg     = tid & 7;           // row-conv col group
    int xq[4];                            // clamped, constant across all rows
#pragma unroll
    for (int q = 0; q < 4; ++q) xq[q] = min(ox0 + cg*4 + q*4, H - 4);

    const int cc  = tid & 31;             // col-conv column
    const int r0c = (tid >> 5) * 4;       // col-conv first row in chunk

    // preload strip rows 0..9 -> slots 0..9
    if (tid < 80) {
        const int y = min(oy0 + r_unit, H - 1);
        row_conv_unit(p1 + (size_t)y*H, p2 + (size_t)y*H, xq, cg,
                      &rp[r_unit][0], P);
    }

    float ssim_acc = 0.f, cs_acc = 0.f;

    for (int t = 0; t < CH; ++t) {
        // ---- row conv: rows t*32+10 .. t*32+41 -> slots 10..41 (1/thread) ----
        {
            const int y = min(oy0 + t*32 + 10 + r_unit, H - 1);
            row_conv_unit(p1 + (size_t)y*H, p2 + (size_t)y*H, xq, cg,
                          &rp[10 + r_unit][0], P);
        }
        __syncthreads();

        // ---- col conv + SSIM: 4 consecutive rows per thread ----
        float A0[4]={0,0,0,0}, A1[4]={0,0,0,0}, A2[4]={0,0,0,0}, A3[4]={0,0,0,0};
#pragma unroll
        for (int k = 0; k < 14; ++k) {
            const float4 v = rp[r0c + k][cc];   // base + k*528B immediate
#pragma unroll
            for (int j = 0; j < 4; ++j) {
                const int tt = k - j;
                if (tt >= 0 && tt < WS) {
                    const float g = P.g[tt];
                    A0[j]+=g*v.x; A1[j]+=g*v.y; A2[j]+=g*v.z; A3[j]+=g*v.w;
                }
            }
        }
        const int ox = ox0 + cc;
#pragma unroll
        for (int j = 0; j < 4; ++j) {
            const int oy = oy0 + t*32 + r0c + j;
            if (oy < OH && ox < OH) {     // OW == OH (square)
                const float ms = A0[j], md = A1[j], Es = A2[j], Ed = A3[j];
                const float ms2 = ms*ms, md2 = md*md;
                const float mu12 = 0.25f * (ms2 - md2);
                const float musq = 0.5f  * (ms2 + md2);             // mu1^2+mu2^2
                const float v1 = 0.5f * (Es - Ed) - 2.f*mu12 + C2V; // 2*sig12+C2
                const float v2 = 0.5f * (Es + Ed) - musq + C2V;     // sig1+sig2+C2
                const float rv2 = __builtin_amdgcn_rcpf(v2);
                const float cs  = v1 * rv2;
                const float ssim = (2.f*mu12 + C1V) *
                                   __builtin_amdgcn_rcpf(musq + C1V) * cs;
                ssim_acc += ssim;
                cs_acc   += cs;
            }
        }

        // ---- fused 2x2 avg pool of this chunk's 32x32 core (1 out/thread) ----
        if (POOL) {
            const int px = tid & 15, py = tid >> 4;
            const int yy = oy0 + t*32 + 2*py;
            const int xx = ox0 + 2*px;
            const float2 a0 = *(const float2*)(p1 + (size_t)yy*H + xx);
            const float2 a1 = *(const float2*)(p1 + (size_t)(yy+1)*H + xx);
            const float2 b0 = *(const float2*)(p2 + (size_t)yy*H + xx);
            const float2 b1 = *(const float2*)(p2 + (size_t)(yy+1)*H + xx);
            const int h = H >> 1;
            const size_t ob = (size_t)img*h*h +
                              (size_t)(((oy0 + t*32) >> 1) + py)*h + (ox0 >> 1) + px;
            pool1[ob] = 0.25f * (a0.x + a0.y + a1.x + a1.y);
            pool2[ob] = 0.25f * (b0.x + b0.y + b1.x + b1.y);
        }

        // ---- carry: slots 32..41 -> slots 0..9 (10 rows x 32 cols = 320 units)
        // write rows 0..9 / read rows 32..41 are disjoint -> race-free.
        if (t + 1 < CH) {
            __syncthreads();              // col-conv reads of slots 0..9 done
            for (int u = tid; u < 320; u += 256) {
                const int r = u >> 5, c = u & 31;
                rp[r][c] = rp[32 + r][c];
            }
            __syncthreads();              // carry done before next row-conv
        }
    }

    // ---- deterministic block reduction -> one partial per block ----
#pragma unroll
    for (int off = 32; off > 0; off >>= 1) {
        ssim_acc += __shfl_down(ssim_acc, off);
        cs_acc   += __shfl_down(cs_acc, off);
    }
    const int wave = tid >> 6, lane = tid & 63;
    if (lane == 0) { reds[wave] = ssim_acc; redc[wave] = cs_acc; }
    __syncthreads();
    if (tid == 0) {
        const float s   = reds[0] + reds[1] + reds[2] + reds[3];
        const float cc2 = redc[0] + redc[1] + redc[2] + redc[3];
        partial[(size_t)partial_off + (size_t)blockIdx.y * gridDim.x + blockIdx.x] =
            make_float2(s, cc2);
    }
}

// ---------------- single fused reduce over all levels + final product ----------------
__global__ __launch_bounds__(256) void reduce_final_kernel(
    const float2* __restrict__ partial, ROff ro, float* __restrict__ out)
{
    __shared__ float sS[5], sC[5];
    __shared__ float reds[4], redc[4];
    const int tid = threadIdx.x;
    for (int l = 0; l < 5; ++l) {
        float s = 0.f, c = 0.f;
        for (int i = tid; i < ro.cnt[l]; i += 256) {
            const float2 v = partial[ro.off[l] + i];
            s += v.x; c += v.y;
        }
#pragma unroll
        for (int off = 32; off > 0; off >>= 1) {
            s += __shfl_down(s, off);
            c += __shfl_down(c, off);
        }
        const int wave = tid >> 6, lane = tid & 63;
        if (lane == 0) { reds[wave] = s; redc[wave] = c; }
        __syncthreads();
        if (tid == 0) {
            sS[l] = (reds[0] + reds[1] + reds[2] + reds[3]) * ro.inv[l];
            sC[l] = (redc[0] + redc[1] + redc[2] + redc[3]) * ro.inv[l];
        }
        __syncthreads();
    }
    if (tid == 0) {
        const float w[5] = {0.0448f, 0.2856f, 0.3001f, 0.2363f, 0.1333f};
        float prod = 1.f;
#pragma unroll
        for (int i = 0; i < 4; ++i)
            prod *= powf((sC[i] + 1.f) * 0.5f, w[i]);
        prod *= powf((sS[4] + 1.f) * 0.5f, w[4]);
        out[0] = prod;
    }
}

// ---------------- host launch ----------------
extern "C" void kernel_launch(void* const* d_in, const int* in_sizes, int n_in,
                              void* d_out, int out_size, void* d_ws, size_t ws_size,
                              hipStream_t stream)
{
    const float* img1 = (const float*)d_in[0];
    const float* img2 = (const float*)d_in[1];
    float* out = (float*)d_out;
    float* ws  = (float*)d_ws;

    // Gaussian window (sigma = 1.5), normalized
    Params P;
    {
        double g[WS], sum = 0.0;
        for (int i = 0; i < WS; ++i) {
            double x = (double)i - (WS / 2);
            g[i] = exp(-x * x / (2.0 * 1.5 * 1.5));
            sum += g[i];
        }
        for (int i = 0; i < WS; ++i) P.g[i] = (float)(g[i] / sum);
    }

    // workspace layout: pyramid levels 1..4 (both images), then partials
    float* p1[5]; float* p2[5];
    p1[0] = (float*)img1; p2[0] = (float*)img2;
    size_t o = 0;
    for (int l = 1; l < 5; ++l) {
        const int H = 512 >> l;
        p1[l] = ws + o; o += (size_t)NC * H * H;
        p2[l] = ws + o; o += (size_t)NC * H * H;
    }
    float2* partial = (float2*)(ws + o);
    (void)ws_size; (void)in_sizes; (void)n_in; (void)out_size;

    const int CHv[5] = {4, 2, 1, 1, 1};   // chunks per strip, per level
    ROff ro;
    {
        int off = 0;
        for (int l = 0; l < 5; ++l) {
            const int H = 512 >> l, OH = H - PAD;
            const int tilesX = (OH + 31) / 32;
            const int tilesY = (OH + CHv[l]*32 - 1) / (CHv[l]*32);
            ro.off[l] = off;
            ro.cnt[l] = tilesX * tilesY * NC;
            ro.inv[l] = 1.f / ((float)NC * OH * OH);
            off += ro.cnt[l];
        }
    }

    for (int l = 0; l < 5; ++l) {
        const int H = 512 >> l, OH = H - PAD;
        const int tilesX = (OH + 31) / 32;
        const int tilesY = (OH + CHv[l]*32 - 1) / (CHv[l]*32);
        const dim3 grid(tilesX * tilesY, NC);
        switch (l) {
        case 0:
            ssim_strip_kernel<4,1><<<grid, 256, 0, stream>>>(
                p1[0], p2[0], p1[1], p2[1], H, OH, tilesX, P, partial, ro.off[0]);
            break;
        case 1:
            ssim_strip_kernel<2,1><<<grid, 256, 0, stream>>>(
                p1[1], p2[1], p1[2], p2[2], H, OH, tilesX, P, partial, ro.off[1]);
            break;
        case 2:
            ssim_strip_kernel<1,1><<<grid, 256, 0, stream>>>(
                p1[2], p2[2], p1[3], p2[3], H, OH, tilesX, P, partial, ro.off[2]);
            break;
        case 3:
            ssim_strip_kernel<1,1><<<grid, 256, 0, stream>>>(
                p1[3], p2[3], p1[4], p2[4], H, OH, tilesX, P, partial, ro.off[3]);
            break;
        default:
            ssim_strip_kernel<1,0><<<grid, 256, 0, stream>>>(
                p1[4], p2[4], nullptr, nullptr, H, OH, tilesX, P, partial, ro.off[4]);
            break;
        }
    }

    reduce_final_kernel<<<1, 256, 0, stream>>>(partial, ro, out);
}